// Round 8
// baseline (248.064 us; speedup 1.0000x reference)
//
#include <hip/hip_runtime.h>
#include <hip/hip_bf16.h>

// MoEProcessor: B=4,S=2048 -> T=8192 tokens, D=1024, E=8, K=2. fp32 in/out.
// Round 8: gemm tile 128x64, 1024 persistent blocks (4/CU resident, 16 waves/CU)
// to fix latency-bound 13% occupancy; xcast fused into routing_compute.

typedef unsigned short u16;
typedef __bf16 bf16x8 __attribute__((ext_vector_type(8)));
typedef float floatx4 __attribute__((ext_vector_type(4)));
typedef unsigned short u16x8 __attribute__((ext_vector_type(8)));
typedef unsigned short u16x4 __attribute__((ext_vector_type(4)));

#define NTOK 8192
#define DDIM 1024
#define NEXP 8

__device__ __forceinline__ u16 f2bf(float f) {
    union { float f; unsigned int i; } c; c.f = f;
    unsigned int i = c.i;
    return (u16)((i + 0x7fffu + ((i >> 16) & 1u)) >> 16);
}

// -------- W_exp transpose+cast: WT[e][f][d] = bf16(W[e][d][f]) --------
__global__ __launch_bounds__(256) void transpose_w(const float* __restrict__ W,
                                                   u16* __restrict__ WT) {
    __shared__ float tileT[64 * 65]; // stride 65: scalar phases 2 lanes/bank (free)
    const int e = blockIdx.z, d0 = blockIdx.y * 64, f0 = blockIdx.x * 64;
    const int t = threadIdx.x;
    const float* src = W + (size_t)e * DDIM * DDIM;
    u16* dst = WT + (size_t)e * DDIM * DDIM;
    const int r = t >> 2, q = t & 3;
    const float* sp = src + (size_t)(d0 + r) * DDIM + f0 + q * 16;
#pragma unroll
    for (int j = 0; j < 4; ++j) {
        float4 v = *(const float4*)(sp + j * 4);
        int c = q * 16 + j * 4;
        tileT[(c + 0) * 65 + r] = v.x;
        tileT[(c + 1) * 65 + r] = v.y;
        tileT[(c + 2) * 65 + r] = v.z;
        tileT[(c + 3) * 65 + r] = v.w;
    }
    __syncthreads();
    const int c2 = t >> 2, dq = (t & 3) * 16;
    u16x8 o0, o1;
#pragma unroll
    for (int i = 0; i < 8; ++i) o0[i] = f2bf(tileT[c2 * 65 + dq + i]);
#pragma unroll
    for (int i = 0; i < 8; ++i) o1[i] = f2bf(tileT[c2 * 65 + dq + 8 + i]);
    u16* dp = dst + (size_t)(f0 + c2) * DDIM + d0 + dq;
    *(u16x8*)dp = o0;
    *(u16x8*)(dp + 8) = o1;
}

// ---- routing_compute (+ fused x->bf16 cast): logits->LN->softmax->+noise->top2 ----
template <int WRITE_XB>
__global__ __launch_bounds__(256) void routing_compute(
    const float* __restrict__ x, const float* __restrict__ noise,
    const float* __restrict__ Wr, const float* __restrict__ br,
    const float* __restrict__ gamma, const float* __restrict__ beta,
    int* __restrict__ e01, float2* __restrict__ w01, u16* __restrict__ xb) {
    __shared__ __align__(16) float wrT[NEXP][DDIM]; // 32 KiB, transposed
    const int t = threadIdx.x;
#pragma unroll
    for (int i = 0; i < 8; ++i) {
        int f4 = i * 256 + t;
        int d = f4 >> 1, half = (f4 & 1) * 4;
        float4 v = *(const float4*)&Wr[d * 8 + half];
        wrT[half + 0][d] = v.x; wrT[half + 1][d] = v.y;
        wrT[half + 2][d] = v.z; wrT[half + 3][d] = v.w;
    }
    __syncthreads();

    const int wave = t >> 6, lane = t & 63;
    const int tok = blockIdx.x * 4 + wave;
    const float4* xrow = (const float4*)(x + (size_t)tok * DDIM);
    float acc[8];
#pragma unroll
    for (int e = 0; e < 8; ++e) acc[e] = 0.f;
#pragma unroll
    for (int i = 0; i < 4; ++i) {
        int d4 = i * 64 + lane;
        float4 xv = xrow[d4];
        if (WRITE_XB) {
            u16x4 o;
            o[0] = f2bf(xv.x); o[1] = f2bf(xv.y); o[2] = f2bf(xv.z); o[3] = f2bf(xv.w);
            *(u16x4*)(xb + (size_t)tok * DDIM + d4 * 4) = o;
        }
#pragma unroll
        for (int e = 0; e < 8; ++e) {
            float4 wv = *(const float4*)&wrT[e][d4 * 4];
            acc[e] += xv.x * wv.x + xv.y * wv.y + xv.z * wv.z + xv.w * wv.w;
        }
    }
#pragma unroll
    for (int off = 32; off >= 1; off >>= 1) {
#pragma unroll
        for (int e = 0; e < 8; ++e) acc[e] += __shfl_xor(acc[e], off, 64);
    }
    if (lane == 0) {
        float lg[8], mu = 0.f;
#pragma unroll
        for (int e = 0; e < 8; ++e) { lg[e] = acc[e] + br[e]; mu += lg[e]; }
        mu *= 0.125f;
        float var = 0.f;
#pragma unroll
        for (int e = 0; e < 8; ++e) { float d = lg[e] - mu; var += d * d; }
        var *= 0.125f;
        float rstd = rsqrtf(var + 1e-5f);
        float ln[8], mx = -1e30f;
#pragma unroll
        for (int e = 0; e < 8; ++e) {
            ln[e] = (lg[e] - mu) * rstd * gamma[e] + beta[e];
            mx = fmaxf(mx, ln[e]);
        }
        float s = 0.f, p[8];
#pragma unroll
        for (int e = 0; e < 8; ++e) { p[e] = expf(ln[e] - mx); s += p[e]; }
        float inv = 1.f / s, r[8];
#pragma unroll
        for (int e = 0; e < 8; ++e) r[e] = p[e] * inv + noise[(size_t)tok * 8 + e];
        int i0 = 0; float v0 = r[0];
#pragma unroll
        for (int e = 1; e < 8; ++e) if (r[e] > v0) { v0 = r[e]; i0 = e; }
        int i1 = -1; float v1 = -1e30f;
#pragma unroll
        for (int e = 0; e < 8; ++e) if (e != i0 && r[e] > v1) { v1 = r[e]; i1 = e; }
        float w0 = 1.f / (1.f + expf(v1 - v0));
        e01[tok] = i0 | (i1 << 8);
        w01[tok] = make_float2(w0, 1.f - w0);
    }
}

// ---- build_lists: one block per (slot,expert) group, ballot-compaction ----
__global__ __launch_bounds__(256) void build_lists(
    const int* __restrict__ e01, const float2* __restrict__ w01,
    int* __restrict__ counts, int* __restrict__ list_tok, float* __restrict__ list_w) {
    const int g = blockIdx.x;            // 0..15: slot = g>>3, expert = g&7
    const int slot = g >> 3, ex = g & 7;
    const int t = threadIdx.x, wave = t >> 6, lane = t & 63;
    __shared__ int wtot[4];
    int base = 0;
    for (int start = 0; start < NTOK; start += 256) {
        int tok = start + t;
        int packed = e01[tok];
        int e = slot ? ((packed >> 8) & 0xff) : (packed & 0xff);
        bool sel = (e == ex);
        unsigned long long m = __ballot(sel);
        int prefix = __popcll(m & ((1ULL << lane) - 1ULL));
        if (lane == 0) wtot[wave] = __popcll(m);
        __syncthreads();
        int wbase = 0;
#pragma unroll
        for (int wv = 0; wv < 4; ++wv) if (wv < wave) wbase += wtot[wv];
        int total = wtot[0] + wtot[1] + wtot[2] + wtot[3];
        if (sel) {
            float2 w2 = w01[tok];
            int pos = base + wbase + prefix;
            list_tok[g * NTOK + pos] = tok;
            list_w[g * NTOK + pos] = slot ? w2.y : w2.x;
        }
        base += total;
        __syncthreads();
    }
    if (t == 0) counts[g] = base;
}

// ------- grouped expert GEMM, tile 128x64: out[tok] (+)= w*(bf16(x)@WT_e + b_e) ----
// Grid 1024: e = id&7 (XCD affinity), n = (id>>3)&15 (64-col tile), mslot = id>>7.
// Persistent m-loop: m0 = mslot*128, +1024. 4 blocks/CU resident (25KB LDS).
template <int BF16A>
__global__ __launch_bounds__(256) void moe_gemm(
    const float* __restrict__ xf, const u16* __restrict__ xb,
    const u16* __restrict__ WT, const float* __restrict__ bexp,
    const int* __restrict__ counts, const int* __restrict__ list_tok,
    const float* __restrict__ list_w, float* __restrict__ out,
    int grp_base, int accum) {
    const int id = blockIdx.x;
    const int e = id & 7;
    const int n = (id >> 3) & 15;
    const int mslot = id >> 7;
    const int grp = grp_base + e;
    int cnt = counts[grp];
    cnt = cnt < 0 ? 0 : (cnt > NTOK ? NTOK : cnt);
    const int n0 = n * 64;

    __shared__ __align__(16) u16 A_s[128 * 64]; // 16 KiB, chunk ^= (row&7)
    __shared__ __align__(16) u16 B_s[64 * 64];  // 8 KiB
    __shared__ int tok_s[128];
    __shared__ float w_s[128];
    __shared__ float bias_s[64];

    const int t = threadIdx.x;
    if (t < 64) bias_s[t] = bexp[e * DDIM + n0 + t];

    const int sr = t >> 3;          // staging row base 0..31
    const int ch = t & 7;           // k-chunk 0..7 (8 u16 = 16B)
    const int co = ch * 8;
    const int cs = ((ch ^ (sr & 7)) << 3);  // swizzled chunk offset (row&7 == sr&7)
    const u16* bsrc = WT + ((size_t)e * DDIM + n0 + sr) * DDIM + co;

    const int lane = t & 63, wave = t >> 6;
    const int wm = wave >> 1, wn = wave & 1;
    const int lm = lane & 15, kc = lane >> 4;

    for (int m0 = mslot * 128; m0 < cnt; m0 += 1024) {
        __syncthreads();            // protect tok_s/w_s from prior epilogue readers
        if (t < 128) {
            int r = m0 + t;
            int rr = r < cnt ? r : cnt - 1;
            tok_s[t] = list_tok[grp * NTOK + rr] & (NTOK - 1);
            w_s[t] = (r < cnt) ? list_w[grp * NTOK + rr] : 0.f;
        }
        __syncthreads();

        size_t arow[4];
#pragma unroll
        for (int s = 0; s < 4; ++s)
            arow[s] = (size_t)tok_s[s * 32 + sr] * DDIM + co;

        floatx4 acc[4][2];
#pragma unroll
        for (int mi = 0; mi < 4; ++mi)
#pragma unroll
            for (int ni = 0; ni < 2; ++ni) acc[mi][ni] = (floatx4){0.f, 0.f, 0.f, 0.f};

        u16x8 pa[4], pb[2];
        float4 pfa[4][2];
#pragma unroll
        for (int s = 0; s < 4; ++s) {
            if (BF16A) {
                pa[s] = *(const u16x8*)(xb + arow[s]);
            } else {
                pfa[s][0] = *(const float4*)(xf + arow[s]);
                pfa[s][1] = *(const float4*)(xf + arow[s] + 4);
            }
        }
#pragma unroll
        for (int s = 0; s < 2; ++s)
            pb[s] = *(const u16x8*)(bsrc + (size_t)s * 32 * DDIM);

        for (int kk = 0; kk < DDIM; kk += 64) {
            u16x8 wa[4];
#pragma unroll
            for (int s = 0; s < 4; ++s) {
                if (BF16A) {
                    wa[s] = pa[s];
                } else {
                    wa[s][0] = f2bf(pfa[s][0].x); wa[s][1] = f2bf(pfa[s][0].y);
                    wa[s][2] = f2bf(pfa[s][0].z); wa[s][3] = f2bf(pfa[s][0].w);
                    wa[s][4] = f2bf(pfa[s][1].x); wa[s][5] = f2bf(pfa[s][1].y);
                    wa[s][6] = f2bf(pfa[s][1].z); wa[s][7] = f2bf(pfa[s][1].w);
                }
            }
            __syncthreads();        // prior iter's ds_reads done before overwrite
#pragma unroll
            for (int s = 0; s < 4; ++s)
                *(u16x8*)(A_s + (s * 32 + sr) * 64 + cs) = wa[s];
#pragma unroll
            for (int s = 0; s < 2; ++s)
                *(u16x8*)(B_s + (s * 32 + sr) * 64 + cs) = pb[s];
            __syncthreads();
            const int nk = kk + 64; // prefetch next iter, overlaps MFMAs below
            if (nk < DDIM) {
#pragma unroll
                for (int s = 0; s < 4; ++s) {
                    if (BF16A) {
                        pa[s] = *(const u16x8*)(xb + arow[s] + nk);
                    } else {
                        pfa[s][0] = *(const float4*)(xf + arow[s] + nk);
                        pfa[s][1] = *(const float4*)(xf + arow[s] + nk + 4);
                    }
                }
#pragma unroll
                for (int s = 0; s < 2; ++s)
                    pb[s] = *(const u16x8*)(bsrc + (size_t)s * 32 * DDIM + nk);
            }
#pragma unroll
            for (int ks = 0; ks < 2; ++ks) {
                bf16x8 af[4], bfr[2];
#pragma unroll
                for (int mi = 0; mi < 4; ++mi) {
                    int row = wm * 64 + mi * 16 + lm;
                    int c = (((ks * 4 + kc) ^ (row & 7)) << 3);
                    af[mi] = *(const bf16x8*)&A_s[row * 64 + c];
                }
#pragma unroll
                for (int ni = 0; ni < 2; ++ni) {
                    int row = wn * 32 + ni * 16 + lm;
                    int c = (((ks * 4 + kc) ^ (row & 7)) << 3);
                    bfr[ni] = *(const bf16x8*)&B_s[row * 64 + c];
                }
#pragma unroll
                for (int mi = 0; mi < 4; ++mi)
#pragma unroll
                    for (int ni = 0; ni < 2; ++ni)
                        acc[mi][ni] = __builtin_amdgcn_mfma_f32_16x16x32_bf16(
                            af[mi], bfr[ni], acc[mi][ni], 0, 0, 0);
            }
        }

        // epilogue: C row = (lane>>4)*4+reg, col = lane&15 within each 16x16 tile
#pragma unroll
        for (int mi = 0; mi < 4; ++mi) {
            int rb = wm * 64 + mi * 16 + (lane >> 4) * 4;
#pragma unroll
            for (int reg = 0; reg < 4; ++reg) {
                int r = rb + reg;
                if (m0 + r < cnt) {
                    size_t tok = (size_t)tok_s[r];
                    float w = w_s[r];
                    float* yrow = out + tok * DDIM + n0;
#pragma unroll
                    for (int ni = 0; ni < 2; ++ni) {
                        int col = wn * 32 + ni * 16 + lm;
                        float v = w * (acc[mi][ni][reg] + bias_s[col]);
                        if (accum) v += yrow[col];
                        yrow[col] = v;
                    }
                }
            }
        }
    }
}

extern "C" void kernel_launch(void* const* d_in, const int* in_sizes, int n_in,
                              void* d_out, int out_size, void* d_ws, size_t ws_size,
                              hipStream_t stream) {
    const float* x     = (const float*)d_in[0];
    const float* noise = (const float*)d_in[1];
    const float* Wr    = (const float*)d_in[2];
    const float* br    = (const float*)d_in[3];
    const float* gamma = (const float*)d_in[4];
    const float* beta  = (const float*)d_in[5];
    const float* Wexp  = (const float*)d_in[6];
    const float* bexp  = (const float*)d_in[7];
    float* out = (float*)d_out;

    unsigned char* ws = (unsigned char*)d_ws;
    u16* WT       = (u16*)ws;                               // 16 MiB
    int* counts   = (int*)(ws + 16777216);                  // 64 B
    int* list_tok = (int*)(ws + 16777472);                  // 512 KiB
    float* list_w = (float*)(ws + 17301760);                // 512 KiB
    int* e01      = (int*)(ws + 17826048);                  // 32 KiB
    float2* w01   = (float2*)(ws + 17858816);               // 64 KiB
    u16* xb       = (u16*)(ws + 17924352);                  // 16 MiB (optional)
    const size_t need_bf16a = 17924352 + 16777216;          // ~33.1 MiB

    transpose_w<<<dim3(16, 16, 8), 256, 0, stream>>>(Wexp, WT);
    if (ws_size >= need_bf16a) {
        routing_compute<1><<<NTOK / 4, 256, 0, stream>>>(x, noise, Wr, br, gamma,
                                                         beta, e01, w01, xb);
        build_lists<<<16, 256, 0, stream>>>(e01, w01, counts, list_tok, list_w);
        moe_gemm<1><<<dim3(1024), 256, 0, stream>>>(
            x, xb, WT, bexp, counts, list_tok, list_w, out, 0, 0);
        moe_gemm<1><<<dim3(1024), 256, 0, stream>>>(
            x, xb, WT, bexp, counts, list_tok, list_w, out, 8, 1);
    } else {
        routing_compute<0><<<NTOK / 4, 256, 0, stream>>>(x, noise, Wr, br, gamma,
                                                         beta, e01, w01, xb);
        build_lists<<<16, 256, 0, stream>>>(e01, w01, counts, list_tok, list_w);
        moe_gemm<0><<<dim3(1024), 256, 0, stream>>>(
            x, xb, WT, bexp, counts, list_tok, list_w, out, 0, 0);
        moe_gemm<0><<<dim3(1024), 256, 0, stream>>>(
            x, xb, WT, bexp, counts, list_tok, list_w, out, 8, 1);
    }
}